// Round 12
// baseline (88.482 us; speedup 1.0000x reference)
//
#include <hip/hip_runtime.h>
#include <hip/hip_bf16.h>

typedef __attribute__((ext_vector_type(8))) _Float16 f16x8;
typedef __attribute__((ext_vector_type(4))) float f32x4;

#define NNODES 8192
#define NEDGES 65536
#define FIN 256
#define FOUT 64
#define EDIM 32

// workspace byte offsets
#define WS_HN    0x000000u   // 2 MB
#define WS_HS    0x200000u   // 2 MB
#define WS_MSG   0x400000u   // 16 MB (slot-order msg = s[e]*hn[src[e]])
#define WS_DEG   0x1400000u  // 32 KB
#define WS_OFF   0x1408000u  // 32 KB
#define WS_RANK  0x1410000u  // 256 KB
#define WS_PERM  0x1450000u  // 256 KB (slot -> edge id)
#define WS_GSRC  0x1490000u  // 256 KB (slot -> src node)
#define WS_WEH   0x14D0000u  // 256 KB fp16 W_edge [col][k]
#define WS_WPREH 0x1510000u  // 32 KB fp16 W_preagg [o][k]
#define WS_WFH   0x1518000u  // 4 KB fp16 Wfold [j][k]
#define WS_BF    0x1519000u  // 256 B f32 bfold[j]
#define WS_WST   0x1520000u  // 16 KB fp32 W_self^T
#define WS_WNT   0x1524000u  // 16 KB fp32 W_neigh^T

__device__ __forceinline__ f16x8 pack8h(float4 v0, float4 v1) {
    f16x8 r;
    r[0] = (_Float16)v0.x; r[1] = (_Float16)v0.y;
    r[2] = (_Float16)v0.z; r[3] = (_Float16)v0.w;
    r[4] = (_Float16)v1.x; r[5] = (_Float16)v1.y;
    r[6] = (_Float16)v1.z; r[7] = (_Float16)v1.w;
    return r;
}

// ---------------- K1: prep (weight transforms + W-fold) || count ----------------
__global__ __launch_bounds__(256) void prep_count_kernel(
    const float* __restrict__ W_edge,
    const float* __restrict__ W_preagg,
    const float* __restrict__ W_self,
    const float* __restrict__ W_neigh,
    const float* __restrict__ b_edge,
    const int* __restrict__ dst,
    _Float16* __restrict__ weh,
    _Float16* __restrict__ wpreh,
    _Float16* __restrict__ wfh,
    float* __restrict__ bfold,
    float* __restrict__ wsT,
    float* __restrict__ wnT,
    int* __restrict__ deg,
    int* __restrict__ rank) {
    int b = blockIdx.x, t = threadIdx.x;
    if (b < 512) {
        int i = b * 256 + t;
        if (i < FOUT * FOUT * EDIM)                   // 131072
            weh[i] = (_Float16)W_edge[i];
        if (i < FOUT * FIN)                           // 16384, row-major [64][256]
            wpreh[i] = (_Float16)W_preagg[i];
        if (i < FOUT * FOUT) {                        // 4096
            int o = i >> 6, k = i & 63;
            wsT[k * FOUT + o] = W_self[i];
            wnT[k * FOUT + o] = W_neigh[i];
        }
    } else if (b < 768) {                             // count
        int e = (b - 512) * 256 + t;
        rank[e] = atomicAdd(deg + dst[e], 1);
    } else {                                          // fold: Wfold[j][k] = sum_i W[i*64+j][k]
        int idx = (b - 768) * 256 + t;                // 0..2047
        int j = idx >> 5, k = idx & 31;
        float s = 0.f;
        #pragma unroll 4
        for (int i = 0; i < 64; ++i)
            s += W_edge[(i * 64 + j) * 32 + k];
        wfh[j * 32 + k] = (_Float16)s;
        if (idx < 64) {
            float sb = 0.f;
            #pragma unroll 4
            for (int i = 0; i < 64; ++i) sb += b_edge[i * 64 + idx];
            bfold[idx] = sb;
        }
    }
}

// ---------------- K2: preagg as single-pass fp16 MFMA GEMM (no LDS) || scan ---------
// wave = 16 rows x 64 outs; 4 waves/block; blocks [0,256) cover 16384 rows; blk 256 = scan
__global__ __launch_bounds__(256) void preagg_scan_kernel(
    const float* __restrict__ h_neigh,
    const float* __restrict__ h_self,
    const _Float16* __restrict__ wpreh,
    const int* __restrict__ deg,
    float* __restrict__ hn,
    float* __restrict__ hs,
    int* __restrict__ off) {
    __shared__ int wsum[4];
    int b = blockIdx.x, t = threadIdx.x;
    if (b == 256) {                      // scan, single block
        int lane = t & 63, w = t >> 6;
        int base = t * 32;
        int loc[32];
        int s = 0;
        #pragma unroll
        for (int i = 0; i < 32; ++i) { loc[i] = s; s += deg[base + i]; }
        int v = s;
        #pragma unroll
        for (int d = 1; d < 64; d <<= 1) {
            int u = __shfl_up(v, d);
            if (lane >= d) v += u;
        }
        if (lane == 63) wsum[w] = v;
        int threadExcl = v - s;
        __syncthreads();
        int wexcl = 0;
        for (int i = 0; i < w; ++i) wexcl += wsum[i];
        int tbase = wexcl + threadExcl;
        #pragma unroll
        for (int i = 0; i < 32; ++i) off[base + i] = tbase + loc[i];
        return;
    }
    int w = t >> 6, lane = t & 63;
    int rowm = lane & 15, kc = lane >> 4;
    int g0 = (b * 4 + w) * 16;           // global row group [g0, g0+16)
    const float* hsrc;
    float* outp;
    int r0;
    if (g0 < NNODES) { hsrc = h_neigh; outp = hn; r0 = g0; }
    else             { hsrc = h_self;  outp = hs; r0 = g0 - NNODES; }
    const float* arow = hsrc + (size_t)(r0 + rowm) * FIN;

    f32x4 acc[4];
    #pragma unroll
    for (int ot = 0; ot < 4; ++ot) acc[ot] = f32x4{0.f, 0.f, 0.f, 0.f};

    #pragma unroll 2
    for (int ks = 0; ks < 8; ++ks) {
        const float* p = arow + ks * 32 + kc * 8;
        float4 v0 = reinterpret_cast<const float4*>(p)[0];
        float4 v1 = reinterpret_cast<const float4*>(p)[1];
        f16x8 af = pack8h(v0, v1);
        #pragma unroll
        for (int ot = 0; ot < 4; ++ot) {
            f16x8 bh = *reinterpret_cast<const f16x8*>(
                wpreh + ((ot * 16 + rowm) * FIN + ks * 32 + kc * 8));
            acc[ot] = __builtin_amdgcn_mfma_f32_16x16x32_f16(af, bh, acc[ot], 0, 0, 0);
        }
    }
    #pragma unroll
    for (int ot = 0; ot < 4; ++ot)
        #pragma unroll
        for (int r = 0; r < 4; ++r)
            outp[(size_t)(r0 + kc * 4 + r) * FOUT + ot * 16 + rowm] =
                fmaxf(acc[ot][r], 0.f);
}

// ---------------- K3: fill slot tables ----------------
__global__ void fill_kernel(const int* __restrict__ src,
                            const int* __restrict__ dst,
                            const int* __restrict__ off,
                            const int* __restrict__ rank,
                            int* __restrict__ perm,
                            int* __restrict__ gsrc) {
    int e = blockIdx.x * 256 + threadIdx.x;
    int slot = off[dst[e]] + rank[e];
    perm[slot] = e;
    gsrc[slot] = src[e];
}

// ---------------- K4: edge GEMM with abs-identity fold --------------------------
// s[e,j] = sum_i relu(x_i) = 0.5*(sum_i x_i + sum_i |x_i|); sum-path via ONE
// prefolded MFMA (Wfold, bfold); |.|-path: d = mfma(a,bh,ZERO) (zero-C is
// loop-invariant -> no per-g cin movs), then sabs += |d + bias| (abs = free
// VOP3 modifier). block = 4 waves = 4 col-quarters; 64 slots/block; grid 1024.
__global__ __launch_bounds__(256) void edge_kernel(
    const float* __restrict__ ef,
    const _Float16* __restrict__ weh,
    const float* __restrict__ b_edge,
    const _Float16* __restrict__ wfh,
    const float* __restrict__ bfold,
    const float* __restrict__ hn,
    const int* __restrict__ perm,
    const int* __restrict__ gsrc,
    float* __restrict__ msg) {
    int t = threadIdx.x;
    int cw = t >> 6, lane = t & 63;
    int rowm = lane & 15, kc = lane >> 4, k0 = kc * 8;
    int e0 = blockIdx.x * 64;
    int colbase = cw * 16 + rowm;

    // A fragments (fp16): lane holds ef[perm[e0 + tt*16 + rowm]][k0 .. k0+8)
    f16x8 a[4];
    #pragma unroll
    for (int tt = 0; tt < 4; ++tt) {
        int eidx = perm[e0 + tt * 16 + rowm];
        const float* p = ef + (size_t)eidx * EDIM + k0;
        float4 v0 = reinterpret_cast<const float4*>(p)[0];
        float4 v1 = reinterpret_cast<const float4*>(p)[1];
        a[tt] = pack8h(v0, v1);
    }

    // folded-sum operands
    f16x8 wf = *reinterpret_cast<const f16x8*>(wfh + colbase * 32 + kc * 8);
    float bf = bfold[colbase];

    f32x4 sabs[4];
    #pragma unroll
    for (int tt = 0; tt < 4; ++tt) sabs[tt] = f32x4{0.f, 0.f, 0.f, 0.f};
    const f32x4 zc = {0.f, 0.f, 0.f, 0.f};   // persistent zero C operand

    unsigned wofs = (unsigned)colbase * 32 + (unsigned)kc * 8;   // fp16 units
    unsigned bofs = (unsigned)colbase;

    #pragma unroll 4
    for (int g = 0; g < 64; ++g) {
        f16x8 bh = *reinterpret_cast<const f16x8*>(weh + wofs);
        float bias = b_edge[bofs];
        wofs += 2048;                    // next col-group: 64 cols * 32 fp16
        bofs += 64;
        #pragma unroll
        for (int tt = 0; tt < 4; ++tt) {
            f32x4 d = __builtin_amdgcn_mfma_f32_16x16x32_f16(a[tt], bh, zc, 0, 0, 0);
            sabs[tt][0] += __builtin_fabsf(d[0] + bias);
            sabs[tt][1] += __builtin_fabsf(d[1] + bias);
            sabs[tt][2] += __builtin_fabsf(d[2] + bias);
            sabs[tt][3] += __builtin_fabsf(d[3] + bias);
        }
    }

    // epilogue: s = 0.5*(sum + sabs); msg[slot][j] = s * hn[gsrc[slot]][j]
    #pragma unroll
    for (int tt = 0; tt < 4; ++tt) {
        f32x4 cin = {bf, bf, bf, bf};
        f32x4 d2 = __builtin_amdgcn_mfma_f32_16x16x32_f16(a[tt], wf, cin, 0, 0, 0);
        #pragma unroll
        for (int r = 0; r < 4; ++r) {
            int slot = e0 + tt * 16 + kc * 4 + r;
            int se = gsrc[slot];
            float hv = 0.5f * hn[(size_t)se * FOUT + colbase];
            msg[(size_t)slot * FOUT + colbase] = (d2[r] + sabs[tt][r]) * hv;
        }
    }
}

// ---------------- K5: final — streaming mean over contiguous slots + two FCs --------
__global__ __launch_bounds__(256) void final_kernel(
    const float* __restrict__ hs,
    const float* __restrict__ msg,
    const int* __restrict__ deg,
    const int* __restrict__ off,
    const float* __restrict__ wsT,
    const float* __restrict__ wnT,
    float* __restrict__ out) {
    __shared__ float sm[4][2][FOUT];
    int t = threadIdx.x, w = t >> 6, lane = t & 63;
    int n = blockIdx.x * 4 + w;
    int o0 = off[n], d = deg[n];
    const float* mp = msg + (size_t)o0 * FOUT + lane;
    float acc = 0.f;
    int i = 0;
    for (; i + 4 <= d; i += 4) {
        float m0 = mp[(size_t)(i + 0) * FOUT];
        float m1 = mp[(size_t)(i + 1) * FOUT];
        float m2 = mp[(size_t)(i + 2) * FOUT];
        float m3 = mp[(size_t)(i + 3) * FOUT];
        acc += (m0 + m1) + (m2 + m3);
    }
    for (; i < d; ++i) acc += mp[(size_t)i * FOUT];
    float neigh = acc / fmaxf((float)d, 1.f);
    sm[w][0][lane] = neigh;
    sm[w][1][lane] = hs[(size_t)n * FOUT + lane];
    __syncthreads();
    float a1 = 0.f, a2 = 0.f;
    #pragma unroll 8
    for (int k = 0; k < FOUT; ++k) {
        a1 = fmaf(sm[w][1][k], wsT[k * FOUT + lane], a1);
        a2 = fmaf(sm[w][0][k], wnT[k * FOUT + lane], a2);
    }
    out[(size_t)n * FOUT + lane] = fmaxf(fmaxf(a1, 0.f) + fmaxf(a2, 0.f), 0.f);
}

extern "C" void kernel_launch(void* const* d_in, const int* in_sizes, int n_in,
                              void* d_out, int out_size, void* d_ws, size_t ws_size,
                              hipStream_t stream) {
    const float* h_neigh  = (const float*)d_in[0];
    const float* h_self   = (const float*)d_in[1];
    const float* ef       = (const float*)d_in[2];
    const float* W_preagg = (const float*)d_in[3];
    const float* W_self   = (const float*)d_in[4];
    const float* W_neigh  = (const float*)d_in[5];
    const float* W_edge   = (const float*)d_in[6];
    const float* b_edge   = (const float*)d_in[7];
    const int*   src      = (const int*)d_in[8];
    const int*   dst      = (const int*)d_in[9];
    float* out = (float*)d_out;
    char* ws = (char*)d_ws;

    float* hn    = (float*)(ws + WS_HN);
    float* hs    = (float*)(ws + WS_HS);
    float* msg   = (float*)(ws + WS_MSG);
    int*   deg   = (int*)(ws + WS_DEG);
    int*   off   = (int*)(ws + WS_OFF);
    int*   rank  = (int*)(ws + WS_RANK);
    int*   perm  = (int*)(ws + WS_PERM);
    int*   gsrc  = (int*)(ws + WS_GSRC);
    _Float16* weh   = (_Float16*)(ws + WS_WEH);
    _Float16* wpreh = (_Float16*)(ws + WS_WPREH);
    _Float16* wfh   = (_Float16*)(ws + WS_WFH);
    float* bfold = (float*)(ws + WS_BF);
    float* wsT   = (float*)(ws + WS_WST);
    float* wnT   = (float*)(ws + WS_WNT);

    // zero deg every call (count accumulates via atomics)
    hipMemsetAsync(ws + WS_DEG, 0, 0x8000, stream);

    prep_count_kernel<<<776, 256, 0, stream>>>(W_edge, W_preagg, W_self, W_neigh,
                                               b_edge, dst, weh, wpreh, wfh, bfold,
                                               wsT, wnT, deg, rank);
    preagg_scan_kernel<<<257, 256, 0, stream>>>(h_neigh, h_self, wpreh, deg,
                                                hn, hs, off);
    fill_kernel<<<NEDGES / 256, 256, 0, stream>>>(src, dst, off, rank, perm, gsrc);
    edge_kernel<<<1024, 256, 0, stream>>>(ef, weh, b_edge, wfh, bfold, hn,
                                          perm, gsrc, msg);
    final_kernel<<<NNODES / 4, 256, 0, stream>>>(hs, msg, deg, off, wsT, wnT, out);
}

// Round 13
// 84.623 us; speedup vs baseline: 1.0456x; 1.0456x over previous
//
#include <hip/hip_runtime.h>
#include <hip/hip_bf16.h>

typedef __attribute__((ext_vector_type(8))) _Float16 f16x8;
typedef __attribute__((ext_vector_type(4))) float f32x4;

#define NNODES 8192
#define NEDGES 65536
#define FIN 256
#define FOUT 64
#define EDIM 32

// workspace byte offsets
#define WS_HN    0x000000u   // 2 MB
#define WS_HS    0x200000u   // 2 MB
#define WS_MSG   0x400000u   // 16 MB (EDGE-order msg = s[e]*hn[src[e]])
#define WS_DEG   0x1400000u  // 32 KB
#define WS_OFF   0x1408000u  // 32 KB
#define WS_RANK  0x1410000u  // 256 KB
#define WS_PERM  0x1450000u  // 256 KB (slot -> edge id)
#define WS_WEH   0x14D0000u  // 256 KB fp16 W_edge [col][k]
#define WS_WPREH 0x1510000u  // 32 KB fp16 W_preagg [o][k]
#define WS_WFH   0x1518000u  // 4 KB fp16 Wfold [j][k]
#define WS_BF    0x1519000u  // 256 B f32 bfold[j]
#define WS_WST   0x1520000u  // 16 KB fp32 W_self^T
#define WS_WNT   0x1524000u  // 16 KB fp32 W_neigh^T

__device__ __forceinline__ f16x8 pack8h(float4 v0, float4 v1) {
    f16x8 r;
    r[0] = (_Float16)v0.x; r[1] = (_Float16)v0.y;
    r[2] = (_Float16)v0.z; r[3] = (_Float16)v0.w;
    r[4] = (_Float16)v1.x; r[5] = (_Float16)v1.y;
    r[6] = (_Float16)v1.z; r[7] = (_Float16)v1.w;
    return r;
}

// ---------------- K1: prep (weight transforms + W-fold) || count ----------------
__global__ __launch_bounds__(256) void prep_count_kernel(
    const float* __restrict__ W_edge,
    const float* __restrict__ W_preagg,
    const float* __restrict__ W_self,
    const float* __restrict__ W_neigh,
    const float* __restrict__ b_edge,
    const int* __restrict__ dst,
    _Float16* __restrict__ weh,
    _Float16* __restrict__ wpreh,
    _Float16* __restrict__ wfh,
    float* __restrict__ bfold,
    float* __restrict__ wsT,
    float* __restrict__ wnT,
    int* __restrict__ deg,
    int* __restrict__ rank) {
    int b = blockIdx.x, t = threadIdx.x;
    if (b < 512) {
        int i = b * 256 + t;
        if (i < FOUT * FOUT * EDIM)                   // 131072
            weh[i] = (_Float16)W_edge[i];
        if (i < FOUT * FIN)                           // 16384, row-major [64][256]
            wpreh[i] = (_Float16)W_preagg[i];
        if (i < FOUT * FOUT) {                        // 4096
            int o = i >> 6, k = i & 63;
            wsT[k * FOUT + o] = W_self[i];
            wnT[k * FOUT + o] = W_neigh[i];
        }
    } else if (b < 768) {                             // count
        int e = (b - 512) * 256 + t;
        rank[e] = atomicAdd(deg + dst[e], 1);
    } else {                                          // fold: Wfold[j][k] = sum_i W[i*64+j][k]
        int idx = (b - 768) * 256 + t;                // 0..2047
        int j = idx >> 5, k = idx & 31;
        float s = 0.f;
        #pragma unroll 4
        for (int i = 0; i < 64; ++i)
            s += W_edge[(i * 64 + j) * 32 + k];       // coalesced per i-slice
        wfh[j * 32 + k] = (_Float16)s;
        if (idx < 64) {
            float sb = 0.f;
            #pragma unroll 4
            for (int i = 0; i < 64; ++i) sb += b_edge[i * 64 + idx];
            bfold[idx] = sb;
        }
    }
}

// ---------------- K2: preagg as single-pass fp16 MFMA GEMM (no LDS) || scan ---------
__global__ __launch_bounds__(256) void preagg_scan_kernel(
    const float* __restrict__ h_neigh,
    const float* __restrict__ h_self,
    const _Float16* __restrict__ wpreh,
    const int* __restrict__ deg,
    float* __restrict__ hn,
    float* __restrict__ hs,
    int* __restrict__ off) {
    __shared__ int wsum[4];
    int b = blockIdx.x, t = threadIdx.x;
    if (b == 256) {                      // scan, single block
        int lane = t & 63, w = t >> 6;
        int base = t * 32;
        int loc[32];
        int s = 0;
        #pragma unroll
        for (int i = 0; i < 32; ++i) { loc[i] = s; s += deg[base + i]; }
        int v = s;
        #pragma unroll
        for (int d = 1; d < 64; d <<= 1) {
            int u = __shfl_up(v, d);
            if (lane >= d) v += u;
        }
        if (lane == 63) wsum[w] = v;
        int threadExcl = v - s;
        __syncthreads();
        int wexcl = 0;
        for (int i = 0; i < w; ++i) wexcl += wsum[i];
        int tbase = wexcl + threadExcl;
        #pragma unroll
        for (int i = 0; i < 32; ++i) off[base + i] = tbase + loc[i];
        return;
    }
    int w = t >> 6, lane = t & 63;
    int rowm = lane & 15, kc = lane >> 4;
    int g0 = (b * 4 + w) * 16;           // global row group [g0, g0+16)
    const float* hsrc;
    float* outp;
    int r0;
    if (g0 < NNODES) { hsrc = h_neigh; outp = hn; r0 = g0; }
    else             { hsrc = h_self;  outp = hs; r0 = g0 - NNODES; }
    const float* arow = hsrc + (size_t)(r0 + rowm) * FIN;

    f32x4 acc[4];
    #pragma unroll
    for (int ot = 0; ot < 4; ++ot) acc[ot] = f32x4{0.f, 0.f, 0.f, 0.f};

    #pragma unroll 2
    for (int ks = 0; ks < 8; ++ks) {
        const float* p = arow + ks * 32 + kc * 8;
        float4 v0 = reinterpret_cast<const float4*>(p)[0];
        float4 v1 = reinterpret_cast<const float4*>(p)[1];
        f16x8 af = pack8h(v0, v1);
        #pragma unroll
        for (int ot = 0; ot < 4; ++ot) {
            f16x8 bh = *reinterpret_cast<const f16x8*>(
                wpreh + ((ot * 16 + rowm) * FIN + ks * 32 + kc * 8));
            acc[ot] = __builtin_amdgcn_mfma_f32_16x16x32_f16(af, bh, acc[ot], 0, 0, 0);
        }
    }
    #pragma unroll
    for (int ot = 0; ot < 4; ++ot)
        #pragma unroll
        for (int r = 0; r < 4; ++r)
            outp[(size_t)(r0 + kc * 4 + r) * FOUT + ot * 16 + rowm] =
                fmaxf(acc[ot][r], 0.f);
}

// ---------------- K3: edge GEMM (natural order) || fill ----------------
// edge blocks [0,1024): abs-identity fold, bias folded into MFMA C-operand:
//   d = mfma(a, bh, {bias}) ; sabs += |d|   -> 1 VALU/elem + 4 movs/g
// fill blocks [1024,1280): perm[off[dst]+rank] = e (edge doesn't need it; final does)
__global__ __launch_bounds__(256) void edge_fill_kernel(
    const float* __restrict__ ef,
    const _Float16* __restrict__ weh,
    const float* __restrict__ b_edge,
    const _Float16* __restrict__ wfh,
    const float* __restrict__ bfold,
    const float* __restrict__ hn,
    const int* __restrict__ src,
    const int* __restrict__ dst,
    const int* __restrict__ off,
    const int* __restrict__ rank,
    float* __restrict__ msg,
    int* __restrict__ perm) {
    int b = blockIdx.x, t = threadIdx.x;
    if (b >= 1024) {                     // fill
        int e = (b - 1024) * 256 + t;
        perm[off[dst[e]] + rank[e]] = e;
        return;
    }
    int cw = t >> 6, lane = t & 63;
    int rowm = lane & 15, kc = lane >> 4, k0 = kc * 8;
    int e0 = b * 64;
    int colbase = cw * 16 + rowm;

    // A fragments (fp16), sequential rows: ef[e0 + tt*16 + rowm][k0..k0+8)
    f16x8 a[4];
    #pragma unroll
    for (int tt = 0; tt < 4; ++tt) {
        const float* p = ef + (size_t)(e0 + tt * 16 + rowm) * EDIM + k0;
        float4 v0 = reinterpret_cast<const float4*>(p)[0];
        float4 v1 = reinterpret_cast<const float4*>(p)[1];
        a[tt] = pack8h(v0, v1);
    }

    // folded-sum operands
    f16x8 wf = *reinterpret_cast<const f16x8*>(wfh + colbase * 32 + kc * 8);
    float bf = bfold[colbase];

    f32x4 sabs[4];
    #pragma unroll
    for (int tt = 0; tt < 4; ++tt) sabs[tt] = f32x4{0.f, 0.f, 0.f, 0.f};

    unsigned wofs = (unsigned)colbase * 32 + (unsigned)kc * 8;   // fp16 units
    unsigned bofs = (unsigned)colbase;

    #pragma unroll 4
    for (int g = 0; g < 64; ++g) {
        f16x8 bh = *reinterpret_cast<const f16x8*>(weh + wofs);
        float bias = b_edge[bofs];
        wofs += 2048;                    // next col-group: 64 cols * 32 fp16
        bofs += 64;
        f32x4 cin = {bias, bias, bias, bias};   // shared by all 4 tiles
        #pragma unroll
        for (int tt = 0; tt < 4; ++tt) {
            f32x4 d = __builtin_amdgcn_mfma_f32_16x16x32_f16(a[tt], bh, cin, 0, 0, 0);
            sabs[tt][0] += __builtin_fabsf(d[0]);
            sabs[tt][1] += __builtin_fabsf(d[1]);
            sabs[tt][2] += __builtin_fabsf(d[2]);
            sabs[tt][3] += __builtin_fabsf(d[3]);
        }
    }

    // epilogue: s = 0.5*(sum + sabs); msg[e][j] = s * hn[src[e]][j]
    #pragma unroll
    for (int tt = 0; tt < 4; ++tt) {
        f32x4 cinf = {bf, bf, bf, bf};
        f32x4 d2 = __builtin_amdgcn_mfma_f32_16x16x32_f16(a[tt], wf, cinf, 0, 0, 0);
        #pragma unroll
        for (int r = 0; r < 4; ++r) {
            int e = e0 + tt * 16 + kc * 4 + r;
            int se = src[e];
            float hv = 0.5f * hn[(size_t)se * FOUT + colbase];
            msg[(size_t)e * FOUT + colbase] = (d2[r] + sabs[tt][r]) * hv;
        }
    }
}

// ---------------- K4: final — CSR gather mean + two FCs ----------------
__global__ __launch_bounds__(256) void final_kernel(
    const float* __restrict__ hs,
    const float* __restrict__ msg,
    const int* __restrict__ deg,
    const int* __restrict__ off,
    const int* __restrict__ perm,
    const float* __restrict__ wsT,
    const float* __restrict__ wnT,
    float* __restrict__ out) {
    __shared__ float sm[4][2][FOUT];
    int t = threadIdx.x, w = t >> 6, lane = t & 63;
    int n = blockIdx.x * 4 + w;
    int o0 = off[n], d = deg[n];
    float acc = 0.f;
    int i = 0;
    for (; i + 2 <= d; i += 2) {
        int ea = perm[o0 + i], eb = perm[o0 + i + 1];
        float ma = msg[(size_t)ea * FOUT + lane];
        float mb = msg[(size_t)eb * FOUT + lane];
        acc += ma + mb;
    }
    if (i < d) acc += msg[(size_t)perm[o0 + i] * FOUT + lane];
    float neigh = acc / fmaxf((float)d, 1.f);
    sm[w][0][lane] = neigh;
    sm[w][1][lane] = hs[(size_t)n * FOUT + lane];
    __syncthreads();
    float a1 = 0.f, a2 = 0.f;
    #pragma unroll 8
    for (int k = 0; k < FOUT; ++k) {
        a1 = fmaf(sm[w][1][k], wsT[k * FOUT + lane], a1);
        a2 = fmaf(sm[w][0][k], wnT[k * FOUT + lane], a2);
    }
    out[(size_t)n * FOUT + lane] = fmaxf(fmaxf(a1, 0.f) + fmaxf(a2, 0.f), 0.f);
}

extern "C" void kernel_launch(void* const* d_in, const int* in_sizes, int n_in,
                              void* d_out, int out_size, void* d_ws, size_t ws_size,
                              hipStream_t stream) {
    const float* h_neigh  = (const float*)d_in[0];
    const float* h_self   = (const float*)d_in[1];
    const float* ef       = (const float*)d_in[2];
    const float* W_preagg = (const float*)d_in[3];
    const float* W_self   = (const float*)d_in[4];
    const float* W_neigh  = (const float*)d_in[5];
    const float* W_edge   = (const float*)d_in[6];
    const float* b_edge   = (const float*)d_in[7];
    const int*   src      = (const int*)d_in[8];
    const int*   dst      = (const int*)d_in[9];
    float* out = (float*)d_out;
    char* ws = (char*)d_ws;

    float* hn    = (float*)(ws + WS_HN);
    float* hs    = (float*)(ws + WS_HS);
    float* msg   = (float*)(ws + WS_MSG);
    int*   deg   = (int*)(ws + WS_DEG);
    int*   off   = (int*)(ws + WS_OFF);
    int*   rank  = (int*)(ws + WS_RANK);
    int*   perm  = (int*)(ws + WS_PERM);
    _Float16* weh   = (_Float16*)(ws + WS_WEH);
    _Float16* wpreh = (_Float16*)(ws + WS_WPREH);
    _Float16* wfh   = (_Float16*)(ws + WS_WFH);
    float* bfold = (float*)(ws + WS_BF);
    float* wsT   = (float*)(ws + WS_WST);
    float* wnT   = (float*)(ws + WS_WNT);

    // zero deg every call (count accumulates via atomics)
    hipMemsetAsync(ws + WS_DEG, 0, 0x8000, stream);

    prep_count_kernel<<<776, 256, 0, stream>>>(W_edge, W_preagg, W_self, W_neigh,
                                               b_edge, dst, weh, wpreh, wfh, bfold,
                                               wsT, wnT, deg, rank);
    preagg_scan_kernel<<<257, 256, 0, stream>>>(h_neigh, h_self, wpreh, deg,
                                                hn, hs, off);
    edge_fill_kernel<<<1280, 256, 0, stream>>>(ef, weh, b_edge, wfh, bfold, hn,
                                               src, dst, off, rank, msg, perm);
    final_kernel<<<NNODES / 4, 256, 0, stream>>>(hs, msg, deg, off, perm,
                                                 wsT, wnT, out);
}